// Round 4
// baseline (266.307 us; speedup 1.0000x reference)
//
#include <hip/hip_runtime.h>
#include <hip/hip_bf16.h>

#define FEATS 1024
#define NH 16
#define HD 64
#define SEQ 2048
#define BATCH 2
#define MTOT (BATCH*SEQ)   // 4096
#define MLPH 4096

typedef __attribute__((ext_vector_type(8))) short bf16x8;   // 8 bf16 (4 VGPRs)
typedef __attribute__((ext_vector_type(4))) short bf16x4;   // 4 bf16 (2 VGPRs)
typedef __attribute__((ext_vector_type(4))) float f32x4;

static_assert(sizeof(bf16x8) == 16, "bf16x8 must be 16B");

__device__ __forceinline__ unsigned short f2bf(float f) {
    unsigned int u = __float_as_uint(f);
    unsigned int lsb = (u >> 16) & 1u;
    u += 0x7fffu + lsb;              // round-to-nearest-even
    return (unsigned short)(u >> 16);
}

// async global->LDS, 16B per lane. Dest must be wave-uniform base + lane*16.
#define ASYNC16(GP, LP) __builtin_amdgcn_global_load_lds( \
    (const __attribute__((address_space(1))) void*)(GP),  \
    (__attribute__((address_space(3))) void*)(LP), 16, 0, 0)

// ---------------------------------------------------------------- converts
__global__ __launch_bounds__(256) void cvt_kernel(const float* __restrict__ src,
                                                  unsigned short* __restrict__ dst, int n) {
    int i = (blockIdx.x * 256 + threadIdx.x) * 4;
    if (i + 3 < n) {
        float4 v = *(const float4*)(src + i);
        ushort4 o;
        o.x = f2bf(v.x); o.y = f2bf(v.y); o.z = f2bf(v.z); o.w = f2bf(v.w);
        *(ushort4*)(dst + i) = o;
    }
}

__global__ __launch_bounds__(256) void concat3_kernel(const float* __restrict__ a,
                                                      const float* __restrict__ b,
                                                      const float* __restrict__ c,
                                                      float* __restrict__ o) {
    int i = blockIdx.x * 256 + threadIdx.x;   // 3072 total
    float v = (i < 1024) ? a[i] : ((i < 2048) ? b[i - 1024] : c[i - 2048]);
    o[i] = v;
}

// ---------------------------------------------------------------- layernorm
__global__ __launch_bounds__(256) void ln_kernel(const float* __restrict__ x,
                                                 const float* __restrict__ g,
                                                 const float* __restrict__ bta,
                                                 unsigned short* __restrict__ h) {
    __shared__ float red[8];
    const int row = blockIdx.x;
    const int t = threadIdx.x;
    const float* xr = x + (size_t)row * FEATS;
    float4 v = ((const float4*)xr)[t];
    float s  = v.x + v.y + v.z + v.w;
    float ss = v.x * v.x + v.y * v.y + v.z * v.z + v.w * v.w;
#pragma unroll
    for (int off = 1; off < 64; off <<= 1) {
        s  += __shfl_xor(s, off);
        ss += __shfl_xor(ss, off);
    }
    const int w = t >> 6;
    if ((t & 63) == 0) { red[w] = s; red[4 + w] = ss; }
    __syncthreads();
    s  = red[0] + red[1] + red[2] + red[3];
    ss = red[4] + red[5] + red[6] + red[7];
    const float mu  = s * (1.f / FEATS);
    const float var = ss * (1.f / FEATS) - mu * mu;
    const float rs  = rsqrtf(var + 1e-5f);
    float4 gv = ((const float4*)g)[t];
    float4 bv = ((const float4*)bta)[t];
    ushort4 ov;
    ov.x = f2bf((v.x - mu) * rs * gv.x + bv.x);
    ov.y = f2bf((v.y - mu) * rs * gv.y + bv.y);
    ov.z = f2bf((v.z - mu) * rs * gv.z + bv.z);
    ov.w = f2bf((v.w - mu) * rs * gv.w + bv.w);
    ((ushort4*)h)[(size_t)row * (FEATS / 4) + t] = ov;
}

// ---------------------------------------------------------------- GEMM
// C[M,N] = epilogue(A[M,K] @ W[N,K]^T + bias); 128x128 tile, BK=32.
// Depth-2 pipeline: 3 LDS buffers, counted vmcnt(4), raw s_barrier.
template <bool RELU, bool ADD, bool OUTBF16>
__global__ __launch_bounds__(256, 2)
void gemm_kernel(const unsigned short* __restrict__ A,
                 const unsigned short* __restrict__ W,
                 const float* __restrict__ bias,
                 const float* __restrict__ addend,
                 void* __restrict__ outp,
                 int M, int N, int K, int gx) {
    __shared__ unsigned short lds[3][2][128 * 32];   // [buf][A=0/B=1][row*32+col]

    const int t = threadIdx.x;
    const int w = t >> 6, lane = t & 63;
    const int wr = w >> 1, wc = w & 1;
    const int li = lane & 15, lj = lane >> 4;

    const int nwg = gridDim.x;
    const int cpx = nwg >> 3;
    const int wg = blockIdx.x;
    const int swz = (wg & 7) * cpx + (wg >> 3);
    const int mb = (swz / gx) * 128, nb = (swz % gx) * 128;

    const int srow = lane >> 2, sc = (lane & 3) * 8;
    const unsigned short* gA = A + (size_t)(mb + w * 16 + srow) * K + sc;
    const unsigned short* gB = W + (size_t)(nb + w * 16 + srow) * K + sc;
    const size_t half = (size_t)64 * K;
    const int lbase = w * 512 + lane * 8;

    const int nt = K >> 5;

#define STAGE(BUF, K0)                                             \
    do {                                                           \
        unsigned short* la_ = &lds[BUF][0][lbase];                 \
        unsigned short* lb_ = &lds[BUF][1][lbase];                 \
        ASYNC16(gA + (K0), la_);                                   \
        ASYNC16(gA + half + (K0), la_ + 2048);                     \
        ASYNC16(gB + (K0), lb_);                                   \
        ASYNC16(gB + half + (K0), lb_ + 2048);                     \
    } while (0)

    STAGE(0, 0);
    STAGE(1, 32);
    asm volatile("s_waitcnt vmcnt(4)" ::: "memory");
    __builtin_amdgcn_s_barrier();

    f32x4 acc[4][4] = {};

    for (int i = 0; i < nt; ++i) {
        const int cur = i % 3;
        const unsigned short* Al = &lds[cur][0][0];
        const unsigned short* Bl = &lds[cur][1][0];

        bf16x8 af[4], bfr[4];
#pragma unroll
        for (int m = 0; m < 4; m++)
            af[m] = *(const bf16x8*)(Al + (wr * 64 + m * 16 + li) * 32 + lj * 8);
#pragma unroll
        for (int n = 0; n < 4; n++)
            bfr[n] = *(const bf16x8*)(Bl + (wc * 64 + n * 16 + li) * 32 + lj * 8);

        const int pf = i + 2 < nt;
        if (pf) STAGE((i + 2) % 3, (i + 2) * 32);

#pragma unroll
        for (int m = 0; m < 4; m++)
#pragma unroll
            for (int n = 0; n < 4; n++)
                acc[m][n] = __builtin_amdgcn_mfma_f32_16x16x32_bf16(af[m], bfr[n], acc[m][n], 0, 0, 0);

        if (i + 1 < nt) {
            if (pf) asm volatile("s_waitcnt vmcnt(4)" ::: "memory");
            else    asm volatile("s_waitcnt vmcnt(0)" ::: "memory");
            __builtin_amdgcn_s_barrier();
        }
    }
#undef STAGE

#pragma unroll
    for (int m = 0; m < 4; m++) {
#pragma unroll
        for (int n = 0; n < 4; n++) {
            const int col = nb + wc * 64 + n * 16 + li;
            const float bv = bias[col];
#pragma unroll
            for (int r = 0; r < 4; r++) {
                const int row = mb + wr * 64 + m * 16 + lj * 4 + r;
                float v = acc[m][n][r] + bv;
                if (RELU) v = fmaxf(v, 0.f);
                if (ADD)  v += addend[(size_t)row * N + col];
                if (OUTBF16)
                    ((unsigned short*)outp)[(size_t)row * N + col] = f2bf(v);
                else
                    ((float*)outp)[(size_t)row * N + col] = v;
            }
        }
    }
}

// ---------------------------------------------------------------- V transpose
__global__ __launch_bounds__(256) void vtrans_kernel(const unsigned short* __restrict__ qkv,
                                                     unsigned short* __restrict__ vt) {
    constexpr int LDV = 68;
    __shared__ unsigned short Vl[64 * LDV];
    const int bh = blockIdx.x, st = blockIdx.y;
    const int b = bh >> 4, h = bh & 15;
    const int t = threadIdx.x;
    const unsigned short* src = qkv + (size_t)(b * SEQ + st * 64) * (3 * FEATS) + 2 * FEATS + h * HD;
#pragma unroll
    for (int i = 0; i < 2; i++) {
        int idx = t + i * 256;
        int r = idx >> 3, c = (idx & 7) * 8;
        *(bf16x8*)(Vl + r * LDV + c) = *(const bf16x8*)(src + (size_t)r * (3 * FEATS) + c);
    }
    __syncthreads();
    unsigned short* dst = vt + (size_t)bh * HD * SEQ + st * 64;
#pragma unroll
    for (int i = 0; i < 2; i++) {
        int idx = t + i * 256;
        int d = idx >> 3, s8 = (idx & 7) * 8;
        bf16x8 v;
#pragma unroll
        for (int j = 0; j < 8; j++) v[j] = Vl[(s8 + j) * LDV + d];
        *(bf16x8*)(dst + (size_t)d * SEQ + s8) = v;
    }
}

// ---------------------------------------------------------------- attention
// 512 thr (8 waves x 16 q-rows). KV tile 64. 3-buffer ASYNC16 pipeline with
// counted vmcnt; XOR-swizzled K/V^T LDS (both-sides); P^T via cvt_pk +
// ds_write_b64; PV A-operand via ds_read_b64_tr_b16 gather.
__global__ __launch_bounds__(512, 4)
void attn_kernel(const unsigned short* __restrict__ qkv,
                 const unsigned short* __restrict__ vt,
                 unsigned short* __restrict__ out) {
    __shared__ unsigned short Kl[3][64 * 64];
    __shared__ unsigned short Vtl[3][64 * 64];
    __shared__ unsigned short Pt[8][64 * 16];   // per-wave P^T [key][q]

    const int bh = blockIdx.x;
    const int b = bh >> 4, h = bh & 15;
    const int q0 = blockIdx.y * 128;
    const int t = threadIdx.x, w = t >> 6, lane = t & 63;
    const int li = lane & 15, lj = lane >> 4;
    const int e7 = li & 7;

    const size_t rstr = 3 * FEATS;
    const unsigned short* qkvb = qkv + (size_t)(b * SEQ) * rstr;

    // staging: row sr = t>>3 (64 rows), 16B slot t&7; global col pre-swizzled
    const int sr = t >> 3;
    const int sslot = (t & 7) ^ (sr & 7);
    const unsigned short* kBase = qkvb + FEATS + h * HD + (size_t)sr * rstr + sslot * 8;
    const unsigned short* vBase = vt + (size_t)bh * HD * SEQ + (size_t)sr * SEQ + sslot * 8;
    const int ldst = t * 8;   // linear LDS dest (shorts)

#define STAGEA(BUF, KV0)                                    \
    do {                                                    \
        ASYNC16(kBase + (size_t)(KV0) * rstr, &Kl[BUF][ldst]); \
        ASYNC16(vBase + (KV0), &Vtl[BUF][ldst]);            \
    } while (0)

    // Q fragments in registers (wave's 16 q-rows)
    bf16x8 aq[2];
#pragma unroll
    for (int kk = 0; kk < 2; kk++)
        aq[kk] = *(const bf16x8*)(qkvb + (size_t)(q0 + w * 16 + li) * rstr + h * HD + kk * 32 + lj * 8);

    f32x4 o[4] = {};
    float lsum[4] = {0.f, 0.f, 0.f, 0.f};
    const float c2 = 1.4426950408889634f / 32.0f;  // log2(e)/sqrt(FEATS)

    unsigned short* Ptw = &Pt[w][0];
    const unsigned ptoff =
        (unsigned)(size_t)(__attribute__((address_space(3))) void*)Ptw;
    const unsigned paddr = ptoff + (unsigned)(li * 2 + lj * 128);

    const int nt = SEQ / 64;   // 32
    STAGEA(0, 0);
    STAGEA(1, 64);
    asm volatile("s_waitcnt vmcnt(2)" ::: "memory");
    __builtin_amdgcn_s_barrier();

    for (int i = 0; i < nt; ++i) {
        const unsigned short* Kc = Kl[i % 3];
        const unsigned short* Vc = Vtl[i % 3];

        const int pf = i + 2 < nt;
        if (pf) STAGEA((i + 2) % 3, (i + 2) * 64);

        // ---- S = Q K^T (swizzled Kl reads) ----
        f32x4 s[4];
        __builtin_amdgcn_s_setprio(1);
#pragma unroll
        for (int n = 0; n < 4; n++) {
            const int row = n * 16 + li;
            bf16x8 b0 = *(const bf16x8*)(Kc + row * 64 + ((lj ^ e7) * 8));
            bf16x8 b1 = *(const bf16x8*)(Kc + row * 64 + (((lj + 4) ^ e7) * 8));
            f32x4 acc = {};
            acc = __builtin_amdgcn_mfma_f32_16x16x32_bf16(aq[0], b0, acc, 0, 0, 0);
            acc = __builtin_amdgcn_mfma_f32_16x16x32_bf16(aq[1], b1, acc, 0, 0, 0);
            s[n] = acc;
        }
        __builtin_amdgcn_s_setprio(0);

        // ---- p = exp(s/32); pack pairs; P^T -> LDS as b64 ----
#pragma unroll
        for (int n = 0; n < 4; n++) {
            float p0 = exp2f(s[n][0] * c2);
            float p1 = exp2f(s[n][1] * c2);
            float p2 = exp2f(s[n][2] * c2);
            float p3 = exp2f(s[n][3] * c2);
            lsum[0] += p0; lsum[1] += p1; lsum[2] += p2; lsum[3] += p3;
            unsigned w0, w1;
            asm("v_cvt_pk_bf16_f32 %0, %1, %2" : "=v"(w0) : "v"(p0), "v"(p1));
            asm("v_cvt_pk_bf16_f32 %0, %1, %2" : "=v"(w1) : "v"(p2), "v"(p3));
            uint2 pk; pk.x = w0; pk.y = w1;
            *(uint2*)(Ptw + (n * 16 + li) * 16 + lj * 4) = pk;
        }

        // ---- P^T ready: transpose-gather A-frags ----
        asm volatile("s_waitcnt lgkmcnt(0)" ::: "memory");
        __builtin_amdgcn_sched_barrier(0);
        bf16x4 pa0, pa1, pa2, pa3;
        asm volatile("ds_read_b64_tr_b16 %0, %4 offset:0\n\t"
                     "ds_read_b64_tr_b16 %1, %4 offset:512\n\t"
                     "ds_read_b64_tr_b16 %2, %4 offset:1024\n\t"
                     "ds_read_b64_tr_b16 %3, %4 offset:1536"
                     : "=&v"(pa0), "=&v"(pa1), "=&v"(pa2), "=&v"(pa3)
                     : "v"(paddr));
        bf16x8 A0 = __builtin_shufflevector(pa0, pa1, 0, 1, 2, 3, 4, 5, 6, 7);
        bf16x8 A1 = __builtin_shufflevector(pa2, pa3, 0, 1, 2, 3, 4, 5, 6, 7);

        // ---- V^T b64 reads (swizzled), same key-slot permutation ----
        bf16x8 bv[4][2];
#pragma unroll
        for (int n = 0; n < 4; n++) {
            const int row = n * 16 + li;
#pragma unroll
            for (int kk = 0; kk < 2; kk++) {
                bf16x4 vlo = *(const bf16x4*)(Vc + row * 64 +
                    (((kk * 4 + (lj >> 1)) ^ e7) * 8) + (lj & 1) * 4);
                bf16x4 vhi = *(const bf16x4*)(Vc + row * 64 +
                    (((kk * 4 + 2 + (lj >> 1)) ^ e7) * 8) + (lj & 1) * 4);
                bv[n][kk] = __builtin_shufflevector(vlo, vhi, 0, 1, 2, 3, 4, 5, 6, 7);
            }
        }
        asm volatile("s_waitcnt lgkmcnt(0)" ::: "memory");
        __builtin_amdgcn_sched_barrier(0);

        // ---- O += P V ----
        __builtin_amdgcn_s_setprio(1);
#pragma unroll
        for (int n = 0; n < 4; n++) {
            o[n] = __builtin_amdgcn_mfma_f32_16x16x32_bf16(A0, bv[n][0], o[n], 0, 0, 0);
            o[n] = __builtin_amdgcn_mfma_f32_16x16x32_bf16(A1, bv[n][1], o[n], 0, 0, 0);
        }
        __builtin_amdgcn_s_setprio(0);

        if (i + 1 < nt) {
            if (pf) asm volatile("s_waitcnt vmcnt(2)" ::: "memory");
            else    asm volatile("s_waitcnt vmcnt(0)" ::: "memory");
            __builtin_amdgcn_s_barrier();
        }
    }
#undef STAGEA

    // final denominator reduce (over the 16 key-lanes) + output
    float inv[4];
#pragma unroll
    for (int r = 0; r < 4; r++) {
        float sred = lsum[r];
        sred += __shfl_xor(sred, 1);
        sred += __shfl_xor(sred, 2);
        sred += __shfl_xor(sred, 4);
        sred += __shfl_xor(sred, 8);
        inv[r] = 1.f / sred;
    }
    unsigned short* ob = out + (size_t)(b * SEQ + q0 + w * 16) * FEATS + h * HD;
#pragma unroll
    for (int n = 0; n < 4; n++)
#pragma unroll
        for (int r = 0; r < 4; r++)
            ob[(size_t)(lj * 4 + r) * FEATS + n * 16 + li] = f2bf(o[n][r] * inv[r]);
}

// ---------------------------------------------------------------- launch
extern "C" void kernel_launch(void* const* d_in, const int* in_sizes, int n_in,
                              void* d_out, int out_size, void* d_ws, size_t ws_size,
                              hipStream_t stream) {
    const float* x     = (const float*)d_in[0];
    const float* ln1_g = (const float*)d_in[1];
    const float* ln1_b = (const float*)d_in[2];
    const float* wq    = (const float*)d_in[3];
    const float* bq    = (const float*)d_in[4];
    const float* wk    = (const float*)d_in[5];
    const float* bk    = (const float*)d_in[6];
    const float* wv    = (const float*)d_in[7];
    const float* bvv   = (const float*)d_in[8];
    const float* wo    = (const float*)d_in[9];
    const float* bo    = (const float*)d_in[10];
    const float* ln2_g = (const float*)d_in[11];
    const float* ln2_b = (const float*)d_in[12];
    const float* w1    = (const float*)d_in[13];
    const float* b1    = (const float*)d_in[14];
    const float* w2    = (const float*)d_in[15];
    const float* b2    = (const float*)d_in[16];

    // ---- workspace layout (~84 MB) ----
    unsigned short* wqkv_b = (unsigned short*)d_ws;                 // 3072*1024
    unsigned short* wo_b   = wqkv_b + 3072 * 1024;                  // 1024*1024
    unsigned short* w1_b   = wo_b + 1024 * 1024;                    // 4096*1024
    unsigned short* w2_b   = w1_b + 4096 * 1024;                    // 1024*4096
    float*          bqkv   = (float*)(w2_b + 1024 * 4096);          // 3072
    unsigned short* region = (unsigned short*)(bqkv + 3072);
    unsigned short* qkvb   = region;                                // 4096*3072
    unsigned short* hb     = region + (size_t)4096 * 3072;          // 4096*1024 (LN1 out)
    unsigned short* vtb    = hb;                                    // 32*64*2048 (hb dead after QKV gemm)
    unsigned short* a1     = region;                                // 4096*4096 (qkv+vt dead after attn)
    unsigned short* attn_o = region + (size_t)4096 * 4096;          // 4096*1024
    unsigned short* h2     = attn_o;                                // alias (attn_o dead when written)
    float*          out1   = (float*)(attn_o + (size_t)4096 * 1024);// 4096*1024 fp32
    float*          outf   = (float*)d_out;

    dim3 blk(256);

    cvt_kernel<<<1024, blk, 0, stream>>>(wq, wqkv_b, 1024 * 1024);
    cvt_kernel<<<1024, blk, 0, stream>>>(wk, wqkv_b + 1024 * 1024, 1024 * 1024);
    cvt_kernel<<<1024, blk, 0, stream>>>(wv, wqkv_b + 2 * 1024 * 1024, 1024 * 1024);
    cvt_kernel<<<1024, blk, 0, stream>>>(wo, wo_b, 1024 * 1024);
    cvt_kernel<<<4096, blk, 0, stream>>>(w1, w1_b, 4096 * 1024);
    cvt_kernel<<<4096, blk, 0, stream>>>(w2, w2_b, 4096 * 1024);
    concat3_kernel<<<12, blk, 0, stream>>>(bq, bk, bvv, bqkv);

    ln_kernel<<<MTOT, blk, 0, stream>>>(x, ln1_g, ln1_b, hb);

    // fused QKV gemm: (4096,1024) @ (3072,1024)^T ; grid 24x32 = 768 blocks
    gemm_kernel<false, false, true><<<768, blk, 0, stream>>>(
        hb, wqkv_b, bqkv, nullptr, qkvb, MTOT, 3072, FEATS, 24);

    vtrans_kernel<<<dim3(BATCH * NH, SEQ / 64), blk, 0, stream>>>(qkvb, vtb);

    attn_kernel<<<dim3(BATCH * NH, SEQ / 128), dim3(512), 0, stream>>>(qkvb, vtb, attn_o);

    // out proj + residual: grid 8x32 = 256 blocks
    gemm_kernel<false, true, false><<<256, blk, 0, stream>>>(
        attn_o, wo_b, bo, x, out1, MTOT, FEATS, FEATS, 8);

    ln_kernel<<<MTOT, blk, 0, stream>>>(out1, ln2_g, ln2_b, h2);

    // MLP1: grid 32x32 = 1024 blocks
    gemm_kernel<true, false, true><<<1024, blk, 0, stream>>>(
        h2, w1_b, b1, nullptr, a1, MTOT, MLPH, FEATS, 32);

    // MLP2: grid 8x32 = 256 blocks
    gemm_kernel<true, true, false><<<256, blk, 0, stream>>>(
        a1, w2_b, b2, out1, outf, MTOT, FEATS, MLPH, 8);
}

// Round 5
// 259.930 us; speedup vs baseline: 1.0245x; 1.0245x over previous
//
#include <hip/hip_runtime.h>
#include <hip/hip_bf16.h>

#define FEATS 1024
#define NH 16
#define HD 64
#define SEQ 2048
#define BATCH 2
#define MTOT (BATCH*SEQ)   // 4096
#define MLPH 4096

typedef __attribute__((ext_vector_type(8))) short bf16x8;   // 8 bf16 (4 VGPRs)
typedef __attribute__((ext_vector_type(4))) float f32x4;

static_assert(sizeof(bf16x8) == 16, "bf16x8 must be 16B");

__device__ __forceinline__ unsigned short f2bf(float f) {
    unsigned int u = __float_as_uint(f);
    unsigned int lsb = (u >> 16) & 1u;
    u += 0x7fffu + lsb;              // round-to-nearest-even
    return (unsigned short)(u >> 16);
}

// async global->LDS, 16B per lane. Dest must be wave-uniform base + lane*16.
#define ASYNC16(GP, LP) __builtin_amdgcn_global_load_lds( \
    (const __attribute__((address_space(1))) void*)(GP),  \
    (__attribute__((address_space(3))) void*)(LP), 16, 0, 0)

// ---------------------------------------------------------------- converts
__global__ __launch_bounds__(256) void cvt_kernel(const float* __restrict__ src,
                                                  unsigned short* __restrict__ dst, int n) {
    int i = (blockIdx.x * 256 + threadIdx.x) * 4;
    if (i + 3 < n) {
        float4 v = *(const float4*)(src + i);
        ushort4 o;
        o.x = f2bf(v.x); o.y = f2bf(v.y); o.z = f2bf(v.z); o.w = f2bf(v.w);
        *(ushort4*)(dst + i) = o;
    }
}

__global__ __launch_bounds__(256) void concat3_kernel(const float* __restrict__ a,
                                                      const float* __restrict__ b,
                                                      const float* __restrict__ c,
                                                      float* __restrict__ o) {
    int i = blockIdx.x * 256 + threadIdx.x;   // 3072 total
    float v = (i < 1024) ? a[i] : ((i < 2048) ? b[i - 1024] : c[i - 2048]);
    o[i] = v;
}

// ---------------------------------------------------------------- layernorm
__global__ __launch_bounds__(256) void ln_kernel(const float* __restrict__ x,
                                                 const float* __restrict__ g,
                                                 const float* __restrict__ bta,
                                                 unsigned short* __restrict__ h) {
    __shared__ float red[8];
    const int row = blockIdx.x;
    const int t = threadIdx.x;
    const float* xr = x + (size_t)row * FEATS;
    float4 v = ((const float4*)xr)[t];
    float s  = v.x + v.y + v.z + v.w;
    float ss = v.x * v.x + v.y * v.y + v.z * v.z + v.w * v.w;
#pragma unroll
    for (int off = 1; off < 64; off <<= 1) {
        s  += __shfl_xor(s, off);
        ss += __shfl_xor(ss, off);
    }
    const int w = t >> 6;
    if ((t & 63) == 0) { red[w] = s; red[4 + w] = ss; }
    __syncthreads();
    s  = red[0] + red[1] + red[2] + red[3];
    ss = red[4] + red[5] + red[6] + red[7];
    const float mu  = s * (1.f / FEATS);
    const float var = ss * (1.f / FEATS) - mu * mu;
    const float rs  = rsqrtf(var + 1e-5f);
    float4 gv = ((const float4*)g)[t];
    float4 bv = ((const float4*)bta)[t];
    ushort4 ov;
    ov.x = f2bf((v.x - mu) * rs * gv.x + bv.x);
    ov.y = f2bf((v.y - mu) * rs * gv.y + bv.y);
    ov.z = f2bf((v.z - mu) * rs * gv.z + bv.z);
    ov.w = f2bf((v.w - mu) * rs * gv.w + bv.w);
    ((ushort4*)h)[(size_t)row * (FEATS / 4) + t] = ov;
}

// ---------------------------------------------------------------- GEMM
// C[M,N] = epilogue(A[M,K] @ W[N,K]^T + bias); 128x128 tile, BK=32.
// Depth-2 pipeline: 3 LDS buffers, counted vmcnt(4), raw s_barrier.
// launch_bounds(256,3): 3 blocks/CU (48KB LDS x3 = 144KB) for wave overlap.
template <bool RELU, bool ADD, bool OUTBF16>
__global__ __launch_bounds__(256, 3)
void gemm_kernel(const unsigned short* __restrict__ A,
                 const unsigned short* __restrict__ W,
                 const float* __restrict__ bias,
                 const float* __restrict__ addend,
                 void* __restrict__ outp,
                 int M, int N, int K, int gx) {
    __shared__ unsigned short lds[3][2][128 * 32];   // [buf][A=0/B=1][row*32+col]

    const int t = threadIdx.x;
    const int w = t >> 6, lane = t & 63;
    const int wr = w >> 1, wc = w & 1;
    const int li = lane & 15, lj = lane >> 4;

    const int nwg = gridDim.x;
    const int cpx = nwg >> 3;
    const int wg = blockIdx.x;
    const int swz = (wg & 7) * cpx + (wg >> 3);
    const int mb = (swz / gx) * 128, nb = (swz % gx) * 128;

    const int srow = lane >> 2, sc = (lane & 3) * 8;
    const unsigned short* gA = A + (size_t)(mb + w * 16 + srow) * K + sc;
    const unsigned short* gB = W + (size_t)(nb + w * 16 + srow) * K + sc;
    const size_t half = (size_t)64 * K;
    const int lbase = w * 512 + lane * 8;

    const int nt = K >> 5;

#define STAGE(BUF, K0)                                             \
    do {                                                           \
        unsigned short* la_ = &lds[BUF][0][lbase];                 \
        unsigned short* lb_ = &lds[BUF][1][lbase];                 \
        ASYNC16(gA + (K0), la_);                                   \
        ASYNC16(gA + half + (K0), la_ + 2048);                     \
        ASYNC16(gB + (K0), lb_);                                   \
        ASYNC16(gB + half + (K0), lb_ + 2048);                     \
    } while (0)

    STAGE(0, 0);
    STAGE(1, 32);
    asm volatile("s_waitcnt vmcnt(4)" ::: "memory");
    __builtin_amdgcn_s_barrier();

    f32x4 acc[4][4] = {};

    for (int i = 0; i < nt; ++i) {
        const int cur = i % 3;
        const unsigned short* Al = &lds[cur][0][0];
        const unsigned short* Bl = &lds[cur][1][0];

        bf16x8 af[4], bfr[4];
#pragma unroll
        for (int m = 0; m < 4; m++)
            af[m] = *(const bf16x8*)(Al + (wr * 64 + m * 16 + li) * 32 + lj * 8);
#pragma unroll
        for (int n = 0; n < 4; n++)
            bfr[n] = *(const bf16x8*)(Bl + (wc * 64 + n * 16 + li) * 32 + lj * 8);

        const int pf = i + 2 < nt;
        if (pf) STAGE((i + 2) % 3, (i + 2) * 32);

#pragma unroll
        for (int m = 0; m < 4; m++)
#pragma unroll
            for (int n = 0; n < 4; n++)
                acc[m][n] = __builtin_amdgcn_mfma_f32_16x16x32_bf16(af[m], bfr[n], acc[m][n], 0, 0, 0);

        if (i + 1 < nt) {
            if (pf) asm volatile("s_waitcnt vmcnt(4)" ::: "memory");
            else    asm volatile("s_waitcnt vmcnt(0)" ::: "memory");
            __builtin_amdgcn_s_barrier();
        }
    }
#undef STAGE

#pragma unroll
    for (int m = 0; m < 4; m++) {
#pragma unroll
        for (int n = 0; n < 4; n++) {
            const int col = nb + wc * 64 + n * 16 + li;
            const float bv = bias[col];
#pragma unroll
            for (int r = 0; r < 4; r++) {
                const int row = mb + wr * 64 + m * 16 + lj * 4 + r;
                float v = acc[m][n][r] + bv;
                if (RELU) v = fmaxf(v, 0.f);
                if (ADD)  v += addend[(size_t)row * N + col];
                if (OUTBF16)
                    ((unsigned short*)outp)[(size_t)row * N + col] = f2bf(v);
                else
                    ((float*)outp)[(size_t)row * N + col] = v;
            }
        }
    }
}

// ---------------------------------------------------------------- V transpose
__global__ __launch_bounds__(256) void vtrans_kernel(const unsigned short* __restrict__ qkv,
                                                     unsigned short* __restrict__ vt) {
    constexpr int LDV = 68;
    __shared__ unsigned short Vl[64 * LDV];
    const int bh = blockIdx.x, st = blockIdx.y;
    const int b = bh >> 4, h = bh & 15;
    const int t = threadIdx.x;
    const unsigned short* src = qkv + (size_t)(b * SEQ + st * 64) * (3 * FEATS) + 2 * FEATS + h * HD;
#pragma unroll
    for (int i = 0; i < 2; i++) {
        int idx = t + i * 256;
        int r = idx >> 3, c = (idx & 7) * 8;
        *(bf16x8*)(Vl + r * LDV + c) = *(const bf16x8*)(src + (size_t)r * (3 * FEATS) + c);
    }
    __syncthreads();
    unsigned short* dst = vt + (size_t)bh * HD * SEQ + st * 64;
#pragma unroll
    for (int i = 0; i < 2; i++) {
        int idx = t + i * 256;
        int d = idx >> 3, s8 = (idx & 7) * 8;
        bf16x8 v;
#pragma unroll
        for (int j = 0; j < 8; j++) v[j] = Vl[(s8 + j) * LDV + d];
        *(bf16x8*)(dst + (size_t)d * SEQ + s8) = v;
    }
}

// ---------------------------------------------------------------- attention
// 512 thr (8 waves x 16 q-rows), KV tile 64, padded conflict-free LDS.
// T14 pipeline: issue next tile's global loads EARLY, raw barrier with
// lgkmcnt-only drain (loads stay in flight), ds_write the prefetched regs
// LATE (after compute). T5 setprio around both MFMA clusters.
__global__ __launch_bounds__(512, 4)
void attn_kernel(const unsigned short* __restrict__ qkv,
                 const unsigned short* __restrict__ vt,
                 unsigned short* __restrict__ out) {
    constexpr int LK = 72;
    constexpr int LP = 68;
    __shared__ unsigned short Kl[2][64 * LK];
    __shared__ unsigned short Vtl[2][64 * LK];
    __shared__ unsigned short Pl[8][16 * LP];

    const int bh = blockIdx.x;
    const int b = bh >> 4, h = bh & 15;
    const int q0 = blockIdx.y * 128;
    const int t = threadIdx.x, w = t >> 6, lane = t & 63;
    const int li = lane & 15, lj = lane >> 4;

    const size_t rstr = 3 * FEATS;
    const unsigned short* qkvb = qkv + (size_t)(b * SEQ) * rstr;
    const unsigned short* ksrc = qkvb + FEATS + h * HD;
    const unsigned short* vsrc = vt + (size_t)bh * HD * SEQ;

    // Q fragments in registers (wave's 16 q-rows)
    bf16x8 aq[2];
#pragma unroll
    for (int kk = 0; kk < 2; kk++)
        aq[kk] = *(const bf16x8*)(qkvb + (size_t)(q0 + w * 16 + li) * rstr + h * HD + kk * 32 + lj * 8);

    f32x4 o[4] = {};
    float lsum[4] = {0.f, 0.f, 0.f, 0.f};
    const float c2 = 1.4426950408889634f / 32.0f;  // log2(e)/sqrt(FEATS)

    // staging coords: 512 threads cover 64 rows x 8 x 16B
    const int sr = t >> 3, scol = (t & 7) * 8;
    const unsigned short* kg = ksrc + (size_t)sr * rstr + scol;
    const unsigned short* vg = vsrc + (size_t)sr * SEQ + scol;
    const int ldo = sr * LK + scol;

    const int nt = SEQ / 64;   // 32

    // prologue: tile 0 staged
    {
        bf16x8 k0 = *(const bf16x8*)kg;
        bf16x8 v0 = *(const bf16x8*)vg;
        *(bf16x8*)(&Kl[0][ldo])  = k0;
        *(bf16x8*)(&Vtl[0][ldo]) = v0;
    }

    int cur = 0;
    for (int i = 0; i < nt; ++i) {
        // issue next tile's global loads early (hidden under this tile's compute)
        bf16x8 kreg, vreg;
        if (i + 1 < nt) {
            kreg = *(const bf16x8*)(kg + (size_t)(i + 1) * 64 * rstr);
            vreg = *(const bf16x8*)(vg + (i + 1) * 64);
        }

        // barrier: LDS writes of buf[cur] visible; global loads stay in flight
        asm volatile("s_waitcnt lgkmcnt(0)" ::: "memory");
        __builtin_amdgcn_s_barrier();

        const unsigned short* Kc = Kl[cur];
        const unsigned short* Vc = Vtl[cur];

        // ---- S = Q K^T : per wave 16q x 64k ----
        f32x4 s[4];
        __builtin_amdgcn_s_setprio(1);
#pragma unroll
        for (int n = 0; n < 4; n++) {
            bf16x8 b0 = *(const bf16x8*)(Kc + (n * 16 + li) * LK + lj * 8);
            bf16x8 b1 = *(const bf16x8*)(Kc + (n * 16 + li) * LK + 32 + lj * 8);
            f32x4 acc = {};
            acc = __builtin_amdgcn_mfma_f32_16x16x32_bf16(aq[0], b0, acc, 0, 0, 0);
            acc = __builtin_amdgcn_mfma_f32_16x16x32_bf16(aq[1], b1, acc, 0, 0, 0);
            s[n] = acc;
        }
        __builtin_amdgcn_s_setprio(0);

        // ---- p = exp(s/32), partial denominator, P -> LDS bf16 ----
#pragma unroll
        for (int n = 0; n < 4; n++)
#pragma unroll
            for (int r = 0; r < 4; r++) {
                float p = exp2f(s[n][r] * c2);
                lsum[r] += p;
                Pl[w][(lj * 4 + r) * LP + n * 16 + li] = f2bf(p);
            }

        // ---- O += P V ----
        __builtin_amdgcn_s_setprio(1);
#pragma unroll
        for (int kk = 0; kk < 2; kk++) {
            bf16x8 ap = *(const bf16x8*)(Pl[w] + li * LP + kk * 32 + lj * 8);
#pragma unroll
            for (int n = 0; n < 4; n++) {
                bf16x8 bv = *(const bf16x8*)(Vc + (n * 16 + li) * LK + kk * 32 + lj * 8);
                o[n] = __builtin_amdgcn_mfma_f32_16x16x32_bf16(ap, bv, o[n], 0, 0, 0);
            }
        }
        __builtin_amdgcn_s_setprio(0);

        // write-late: prefetched tile into the other buffer
        if (i + 1 < nt) {
            *(bf16x8*)(&Kl[cur ^ 1][ldo])  = kreg;
            *(bf16x8*)(&Vtl[cur ^ 1][ldo]) = vreg;
        }
        cur ^= 1;
    }

    // final denominator reduce (over the 16 key-lanes) + output
    float inv[4];
#pragma unroll
    for (int r = 0; r < 4; r++) {
        float sred = lsum[r];
        sred += __shfl_xor(sred, 1);
        sred += __shfl_xor(sred, 2);
        sred += __shfl_xor(sred, 4);
        sred += __shfl_xor(sred, 8);
        inv[r] = 1.f / sred;
    }
    unsigned short* ob = out + (size_t)(b * SEQ + q0 + w * 16) * FEATS + h * HD;
#pragma unroll
    for (int n = 0; n < 4; n++)
#pragma unroll
        for (int r = 0; r < 4; r++)
            ob[(size_t)(lj * 4 + r) * FEATS + n * 16 + li] = f2bf(o[n][r] * inv[r]);
}

// ---------------------------------------------------------------- launch
extern "C" void kernel_launch(void* const* d_in, const int* in_sizes, int n_in,
                              void* d_out, int out_size, void* d_ws, size_t ws_size,
                              hipStream_t stream) {
    const float* x     = (const float*)d_in[0];
    const float* ln1_g = (const float*)d_in[1];
    const float* ln1_b = (const float*)d_in[2];
    const float* wq    = (const float*)d_in[3];
    const float* bq    = (const float*)d_in[4];
    const float* wk    = (const float*)d_in[5];
    const float* bk    = (const float*)d_in[6];
    const float* wv    = (const float*)d_in[7];
    const float* bvv   = (const float*)d_in[8];
    const float* wo    = (const float*)d_in[9];
    const float* bo    = (const float*)d_in[10];
    const float* ln2_g = (const float*)d_in[11];
    const float* ln2_b = (const float*)d_in[12];
    const float* w1    = (const float*)d_in[13];
    const float* b1    = (const float*)d_in[14];
    const float* w2    = (const float*)d_in[15];
    const float* b2    = (const float*)d_in[16];

    // ---- workspace layout (~84 MB) ----
    unsigned short* wqkv_b = (unsigned short*)d_ws;                 // 3072*1024
    unsigned short* wo_b   = wqkv_b + 3072 * 1024;                  // 1024*1024
    unsigned short* w1_b   = wo_b + 1024 * 1024;                    // 4096*1024
    unsigned short* w2_b   = w1_b + 4096 * 1024;                    // 1024*4096
    float*          bqkv   = (float*)(w2_b + 1024 * 4096);          // 3072
    unsigned short* region = (unsigned short*)(bqkv + 3072);
    unsigned short* qkvb   = region;                                // 4096*3072
    unsigned short* hb     = region + (size_t)4096 * 3072;          // 4096*1024 (LN1 out)
    unsigned short* vtb    = hb;                                    // 32*64*2048 (hb dead after QKV gemm)
    unsigned short* a1     = region;                                // 4096*4096 (qkv+vt dead after attn)
    unsigned short* attn_o = region + (size_t)4096 * 4096;          // 4096*1024
    unsigned short* h2     = attn_o;                                // alias (attn_o dead when written)
    float*          out1   = (float*)(attn_o + (size_t)4096 * 1024);// 4096*1024 fp32
    float*          outf   = (float*)d_out;

    dim3 blk(256);

    cvt_kernel<<<1024, blk, 0, stream>>>(wq, wqkv_b, 1024 * 1024);
    cvt_kernel<<<1024, blk, 0, stream>>>(wk, wqkv_b + 1024 * 1024, 1024 * 1024);
    cvt_kernel<<<1024, blk, 0, stream>>>(wv, wqkv_b + 2 * 1024 * 1024, 1024 * 1024);
    cvt_kernel<<<1024, blk, 0, stream>>>(wo, wo_b, 1024 * 1024);
    cvt_kernel<<<4096, blk, 0, stream>>>(w1, w1_b, 4096 * 1024);
    cvt_kernel<<<4096, blk, 0, stream>>>(w2, w2_b, 4096 * 1024);
    concat3_kernel<<<12, blk, 0, stream>>>(bq, bk, bvv, bqkv);

    ln_kernel<<<MTOT, blk, 0, stream>>>(x, ln1_g, ln1_b, hb);

    // fused QKV gemm: (4096,1024) @ (3072,1024)^T ; grid 24x32 = 768 blocks
    gemm_kernel<false, false, true><<<768, blk, 0, stream>>>(
        hb, wqkv_b, bqkv, nullptr, qkvb, MTOT, 3072, FEATS, 24);

    vtrans_kernel<<<dim3(BATCH * NH, SEQ / 64), blk, 0, stream>>>(qkvb, vtb);

    attn_kernel<<<dim3(BATCH * NH, SEQ / 128), dim3(512), 0, stream>>>(qkvb, vtb, attn_o);

    // out proj + residual: grid 8x32 = 256 blocks
    gemm_kernel<false, true, false><<<256, blk, 0, stream>>>(
        attn_o, wo_b, bo, x, out1, MTOT, FEATS, FEATS, 8);

    ln_kernel<<<MTOT, blk, 0, stream>>>(out1, ln2_g, ln2_b, h2);

    // MLP1: grid 32x32 = 1024 blocks
    gemm_kernel<true, false, true><<<1024, blk, 0, stream>>>(
        h2, w1_b, b1, nullptr, a1, MTOT, MLPH, FEATS, 32);

    // MLP2: grid 8x32 = 256 blocks
    gemm_kernel<true, true, false><<<256, blk, 0, stream>>>(
        a1, w2_b, b2, out1, outf, MTOT, FEATS, MLPH, 8);
}

// Round 6
// 249.380 us; speedup vs baseline: 1.0679x; 1.0423x over previous
//
#include <hip/hip_runtime.h>
#include <hip/hip_bf16.h>

#define FEATS 1024
#define NH 16
#define HD 64
#define SEQ 2048
#define BATCH 2
#define MTOT (BATCH*SEQ)   // 4096
#define MLPH 4096

typedef __attribute__((ext_vector_type(8))) short bf16x8;   // 8 bf16 (4 VGPRs)
typedef __attribute__((ext_vector_type(4))) short bf16x4;   // 4 bf16 (2 VGPRs)
typedef __attribute__((ext_vector_type(4))) float f32x4;

static_assert(sizeof(bf16x8) == 16, "bf16x8 must be 16B");

__device__ __forceinline__ unsigned short f2bf(float f) {
    unsigned int u = __float_as_uint(f);
    unsigned int lsb = (u >> 16) & 1u;
    u += 0x7fffu + lsb;              // round-to-nearest-even
    return (unsigned short)(u >> 16);
}

// async global->LDS, 16B per lane. Dest must be wave-uniform base + lane*16.
#define ASYNC16(GP, LP) __builtin_amdgcn_global_load_lds( \
    (const __attribute__((address_space(1))) void*)(GP),  \
    (__attribute__((address_space(3))) void*)(LP), 16, 0, 0)

// ---------------------------------------------------------------- converts
__global__ __launch_bounds__(256) void cvt_kernel(const float* __restrict__ src,
                                                  unsigned short* __restrict__ dst, int n) {
    int i = (blockIdx.x * 256 + threadIdx.x) * 4;
    if (i + 3 < n) {
        float4 v = *(const float4*)(src + i);
        ushort4 o;
        o.x = f2bf(v.x); o.y = f2bf(v.y); o.z = f2bf(v.z); o.w = f2bf(v.w);
        *(ushort4*)(dst + i) = o;
    }
}

__global__ __launch_bounds__(256) void concat3_kernel(const float* __restrict__ a,
                                                      const float* __restrict__ b,
                                                      const float* __restrict__ c,
                                                      float* __restrict__ o) {
    int i = blockIdx.x * 256 + threadIdx.x;   // 3072 total
    float v = (i < 1024) ? a[i] : ((i < 2048) ? b[i - 1024] : c[i - 2048]);
    o[i] = v;
}

// ---------------------------------------------------------------- layernorm
__global__ __launch_bounds__(256) void ln_kernel(const float* __restrict__ x,
                                                 const float* __restrict__ g,
                                                 const float* __restrict__ bta,
                                                 unsigned short* __restrict__ h) {
    __shared__ float red[8];
    const int row = blockIdx.x;
    const int t = threadIdx.x;
    const float* xr = x + (size_t)row * FEATS;
    float4 v = ((const float4*)xr)[t];
    float s  = v.x + v.y + v.z + v.w;
    float ss = v.x * v.x + v.y * v.y + v.z * v.z + v.w * v.w;
#pragma unroll
    for (int off = 1; off < 64; off <<= 1) {
        s  += __shfl_xor(s, off);
        ss += __shfl_xor(ss, off);
    }
    const int w = t >> 6;
    if ((t & 63) == 0) { red[w] = s; red[4 + w] = ss; }
    __syncthreads();
    s  = red[0] + red[1] + red[2] + red[3];
    ss = red[4] + red[5] + red[6] + red[7];
    const float mu  = s * (1.f / FEATS);
    const float var = ss * (1.f / FEATS) - mu * mu;
    const float rs  = rsqrtf(var + 1e-5f);
    float4 gv = ((const float4*)g)[t];
    float4 bv = ((const float4*)bta)[t];
    ushort4 ov;
    ov.x = f2bf((v.x - mu) * rs * gv.x + bv.x);
    ov.y = f2bf((v.y - mu) * rs * gv.y + bv.y);
    ov.z = f2bf((v.z - mu) * rs * gv.z + bv.z);
    ov.w = f2bf((v.w - mu) * rs * gv.w + bv.w);
    ((ushort4*)h)[(size_t)row * (FEATS / 4) + t] = ov;
}

// ---------------------------------------------------------------- GEMM
// C[M,N] = epilogue(A[M,K] @ W[N,K]^T + bias); 128x128 tile, BK=32.
// Depth-2 pipeline: 3 LDS buffers, counted vmcnt(4), raw s_barrier.
template <bool RELU, bool ADD, bool OUTBF16>
__global__ __launch_bounds__(256, 3)
void gemm_kernel(const unsigned short* __restrict__ A,
                 const unsigned short* __restrict__ W,
                 const float* __restrict__ bias,
                 const float* __restrict__ addend,
                 void* __restrict__ outp,
                 int M, int N, int K, int gx) {
    __shared__ unsigned short lds[3][2][128 * 32];   // [buf][A=0/B=1][row*32+col]

    const int t = threadIdx.x;
    const int w = t >> 6, lane = t & 63;
    const int wr = w >> 1, wc = w & 1;
    const int li = lane & 15, lj = lane >> 4;

    const int nwg = gridDim.x;
    const int cpx = nwg >> 3;
    const int wg = blockIdx.x;
    const int swz = (wg & 7) * cpx + (wg >> 3);
    const int mb = (swz / gx) * 128, nb = (swz % gx) * 128;

    const int srow = lane >> 2, sc = (lane & 3) * 8;
    const unsigned short* gA = A + (size_t)(mb + w * 16 + srow) * K + sc;
    const unsigned short* gB = W + (size_t)(nb + w * 16 + srow) * K + sc;
    const size_t half = (size_t)64 * K;
    const int lbase = w * 512 + lane * 8;

    const int nt = K >> 5;

#define STAGE(BUF, K0)                                             \
    do {                                                           \
        unsigned short* la_ = &lds[BUF][0][lbase];                 \
        unsigned short* lb_ = &lds[BUF][1][lbase];                 \
        ASYNC16(gA + (K0), la_);                                   \
        ASYNC16(gA + half + (K0), la_ + 2048);                     \
        ASYNC16(gB + (K0), lb_);                                   \
        ASYNC16(gB + half + (K0), lb_ + 2048);                     \
    } while (0)

    STAGE(0, 0);
    STAGE(1, 32);
    asm volatile("s_waitcnt vmcnt(4)" ::: "memory");
    __builtin_amdgcn_s_barrier();

    f32x4 acc[4][4] = {};

    for (int i = 0; i < nt; ++i) {
        const int cur = i % 3;
        const unsigned short* Al = &lds[cur][0][0];
        const unsigned short* Bl = &lds[cur][1][0];

        bf16x8 af[4], bfr[4];
#pragma unroll
        for (int m = 0; m < 4; m++)
            af[m] = *(const bf16x8*)(Al + (wr * 64 + m * 16 + li) * 32 + lj * 8);
#pragma unroll
        for (int n = 0; n < 4; n++)
            bfr[n] = *(const bf16x8*)(Bl + (wc * 64 + n * 16 + li) * 32 + lj * 8);

        const int pf = i + 2 < nt;
        if (pf) STAGE((i + 2) % 3, (i + 2) * 32);

#pragma unroll
        for (int m = 0; m < 4; m++)
#pragma unroll
            for (int n = 0; n < 4; n++)
                acc[m][n] = __builtin_amdgcn_mfma_f32_16x16x32_bf16(af[m], bfr[n], acc[m][n], 0, 0, 0);

        if (i + 1 < nt) {
            if (pf) asm volatile("s_waitcnt vmcnt(4)" ::: "memory");
            else    asm volatile("s_waitcnt vmcnt(0)" ::: "memory");
            __builtin_amdgcn_s_barrier();
        }
    }
#undef STAGE

#pragma unroll
    for (int m = 0; m < 4; m++) {
#pragma unroll
        for (int n = 0; n < 4; n++) {
            const int col = nb + wc * 64 + n * 16 + li;
            const float bv = bias[col];
#pragma unroll
            for (int r = 0; r < 4; r++) {
                const int row = mb + wr * 64 + m * 16 + lj * 4 + r;
                float v = acc[m][n][r] + bv;
                if (RELU) v = fmaxf(v, 0.f);
                if (ADD)  v += addend[(size_t)row * N + col];
                if (OUTBF16)
                    ((unsigned short*)outp)[(size_t)row * N + col] = f2bf(v);
                else
                    ((float*)outp)[(size_t)row * N + col] = v;
            }
        }
    }
}

// ---------------------------------------------------------------- V transpose
__global__ __launch_bounds__(256) void vtrans_kernel(const unsigned short* __restrict__ qkv,
                                                     unsigned short* __restrict__ vt) {
    constexpr int LDV = 68;
    __shared__ unsigned short Vl[64 * LDV];
    const int bh = blockIdx.x, st = blockIdx.y;
    const int b = bh >> 4, h = bh & 15;
    const int t = threadIdx.x;
    const unsigned short* src = qkv + (size_t)(b * SEQ + st * 64) * (3 * FEATS) + 2 * FEATS + h * HD;
#pragma unroll
    for (int i = 0; i < 2; i++) {
        int idx = t + i * 256;
        int r = idx >> 3, c = (idx & 7) * 8;
        *(bf16x8*)(Vl + r * LDV + c) = *(const bf16x8*)(src + (size_t)r * (3 * FEATS) + c);
    }
    __syncthreads();
    unsigned short* dst = vt + (size_t)bh * HD * SEQ + st * 64;
#pragma unroll
    for (int i = 0; i < 2; i++) {
        int idx = t + i * 256;
        int d = idx >> 3, s8 = (idx & 7) * 8;
        bf16x8 v;
#pragma unroll
        for (int j = 0; j < 8; j++) v[j] = Vl[(s8 + j) * LDV + d];
        *(bf16x8*)(dst + (size_t)d * SEQ + s8) = v;
    }
}

// ---------------------------------------------------------------- attention
// 512 thr (8 waves x 16 q-rows), KV tile 64. Swapped QK^T: S^T = mfma(K, Q)
// puts P[q=li][16 keys] lane-local -> cvt_pk packs the PV A-fragment
// in-register (no P LDS roundtrip). Key-slot permutation absorbed into the
// V^T staging positions. T14 issue-early/write-late staging; T5 setprio.
__global__ __launch_bounds__(512, 4)
void attn_kernel(const unsigned short* __restrict__ qkv,
                 const unsigned short* __restrict__ vt,
                 unsigned short* __restrict__ out) {
    constexpr int LK = 72;
    __shared__ unsigned short Kl[2][64 * LK];
    __shared__ unsigned short Vtl[2][64 * LK];

    const int bh = blockIdx.x;
    const int b = bh >> 4, h = bh & 15;
    const int q0 = blockIdx.y * 128;
    const int t = threadIdx.x, w = t >> 6, lane = t & 63;
    const int li = lane & 15, lj = lane >> 4;

    const size_t rstr = 3 * FEATS;
    const unsigned short* qkvb = qkv + (size_t)(b * SEQ) * rstr;
    const unsigned short* ksrc = qkvb + FEATS + h * HD;
    const unsigned short* vsrc = vt + (size_t)bh * HD * SEQ;

    // Q fragments in registers: B-operand of S^T = K Q^T (same per-lane data)
    bf16x8 aq[2];
#pragma unroll
    for (int kk = 0; kk < 2; kk++)
        aq[kk] = *(const bf16x8*)(qkvb + (size_t)(q0 + w * 16 + li) * rstr + h * HD + kk * 32 + lj * 8);

    f32x4 o[4] = {};
    float lsum = 0.f;                               // denominator for q = li
    const float c2 = 1.4426950408889634f / 32.0f;   // log2(e)/sqrt(FEATS)

    // staging coords: 512 threads cover 64 rows x 8 x 16B
    const int sr = t >> 3, scol = (t & 7) * 8;
    const unsigned short* kg = ksrc + (size_t)sr * rstr + scol;
    const unsigned short* vg = vsrc + (size_t)sr * SEQ + scol;
    const int ldoK = sr * LK + scol;
    // permuted V^T positions: pos(k) = (k/32)*32 + ((k%16)/4)*8 + ((k%32)/16)*4 + k%4
    const int posA = (scol & 32) + ((scol & 8) << 1) + ((scol & 16) >> 2);
    const int ldoV = sr * LK + posA;   // and +8 for the upper half

    const int nt = SEQ / 64;   // 32

    // prologue: tile 0 staged
    {
        bf16x8 k0 = *(const bf16x8*)kg;
        bf16x8 v0 = *(const bf16x8*)vg;
        *(bf16x8*)(&Kl[0][ldoK]) = k0;
        bf16x4 vlo = __builtin_shufflevector(v0, v0, 0, 1, 2, 3);
        bf16x4 vhi = __builtin_shufflevector(v0, v0, 4, 5, 6, 7);
        *(bf16x4*)(&Vtl[0][ldoV])     = vlo;
        *(bf16x4*)(&Vtl[0][ldoV + 8]) = vhi;
    }

    int cur = 0;
    for (int i = 0; i < nt; ++i) {
        // issue next tile's global loads early (hidden under this tile's compute)
        bf16x8 kreg, vreg;
        if (i + 1 < nt) {
            kreg = *(const bf16x8*)(kg + (size_t)(i + 1) * 64 * rstr);
            vreg = *(const bf16x8*)(vg + (i + 1) * 64);
        }

        // barrier: LDS writes of buf[cur] visible; global loads stay in flight
        asm volatile("s_waitcnt lgkmcnt(0)" ::: "memory");
        __builtin_amdgcn_s_barrier();

        const unsigned short* Kc = Kl[cur];
        const unsigned short* Vc = Vtl[cur];

        // ---- S^T = K Q^T : lane holds S[q=li][key = n*16 + lj*4 + r] ----
        f32x4 s[4];
        __builtin_amdgcn_s_setprio(1);
#pragma unroll
        for (int n = 0; n < 4; n++) {
            bf16x8 k0 = *(const bf16x8*)(Kc + (n * 16 + li) * LK + lj * 8);
            bf16x8 k1 = *(const bf16x8*)(Kc + (n * 16 + li) * LK + 32 + lj * 8);
            f32x4 acc = {};
            acc = __builtin_amdgcn_mfma_f32_16x16x32_bf16(k0, aq[0], acc, 0, 0, 0);
            acc = __builtin_amdgcn_mfma_f32_16x16x32_bf16(k1, aq[1], acc, 0, 0, 0);
            s[n] = acc;
        }
        __builtin_amdgcn_s_setprio(0);

        // ---- p = exp(s/32); pack PV A-fragments fully in-register ----
        float p[4][4];
#pragma unroll
        for (int n = 0; n < 4; n++)
#pragma unroll
            for (int r = 0; r < 4; r++) {
                p[n][r] = exp2f(s[n][r] * c2);
                lsum += p[n][r];
            }
        union { unsigned u[4]; bf16x8 v; } A0u, A1u;
#pragma unroll
        for (int n = 0; n < 2; n++) {
            asm("v_cvt_pk_bf16_f32 %0, %1, %2" : "=v"(A0u.u[n * 2])     : "v"(p[n][0]), "v"(p[n][1]));
            asm("v_cvt_pk_bf16_f32 %0, %1, %2" : "=v"(A0u.u[n * 2 + 1]) : "v"(p[n][2]), "v"(p[n][3]));
            asm("v_cvt_pk_bf16_f32 %0, %1, %2" : "=v"(A1u.u[n * 2])     : "v"(p[n + 2][0]), "v"(p[n + 2][1]));
            asm("v_cvt_pk_bf16_f32 %0, %1, %2" : "=v"(A1u.u[n * 2 + 1]) : "v"(p[n + 2][2]), "v"(p[n + 2][3]));
        }

        // ---- O += P V (V^T rows are key-slot-permuted to match A) ----
        __builtin_amdgcn_s_setprio(1);
#pragma unroll
        for (int n = 0; n < 4; n++) {
            bf16x8 bv0 = *(const bf16x8*)(Vc + (n * 16 + li) * LK + lj * 8);
            bf16x8 bv1 = *(const bf16x8*)(Vc + (n * 16 + li) * LK + 32 + lj * 8);
            o[n] = __builtin_amdgcn_mfma_f32_16x16x32_bf16(A0u.v, bv0, o[n], 0, 0, 0);
            o[n] = __builtin_amdgcn_mfma_f32_16x16x32_bf16(A1u.v, bv1, o[n], 0, 0, 0);
        }
        __builtin_amdgcn_s_setprio(0);

        // write-late: prefetched tile into the other buffer
        if (i + 1 < nt) {
            *(bf16x8*)(&Kl[cur ^ 1][ldoK]) = kreg;
            bf16x4 vlo = __builtin_shufflevector(vreg, vreg, 0, 1, 2, 3);
            bf16x4 vhi = __builtin_shufflevector(vreg, vreg, 4, 5, 6, 7);
            *(bf16x4*)(&Vtl[cur ^ 1][ldoV])     = vlo;
            *(bf16x4*)(&Vtl[cur ^ 1][ldoV + 8]) = vhi;
        }
        cur ^= 1;
    }

    // denominator: full sum for q = li lives across lj groups
    lsum += __shfl_xor(lsum, 16);
    lsum += __shfl_xor(lsum, 32);
    const float dinv = 1.f / lsum;
    // epilogue rows are q' = lj*4 + r -> fetch that q's inv via lane shuffle
    float inv[4];
#pragma unroll
    for (int r = 0; r < 4; r++)
        inv[r] = __shfl(dinv, lj * 4 + r);

    unsigned short* ob = out + (size_t)(b * SEQ + q0 + w * 16) * FEATS + h * HD;
#pragma unroll
    for (int n = 0; n < 4; n++)
#pragma unroll
        for (int r = 0; r < 4; r++)
            ob[(size_t)(lj * 4 + r) * FEATS + n * 16 + li] = f2bf(o[n][r] * inv[r]);
}

// ---------------------------------------------------------------- launch
extern "C" void kernel_launch(void* const* d_in, const int* in_sizes, int n_in,
                              void* d_out, int out_size, void* d_ws, size_t ws_size,
                              hipStream_t stream) {
    const float* x     = (const float*)d_in[0];
    const float* ln1_g = (const float*)d_in[1];
    const float* ln1_b = (const float*)d_in[2];
    const float* wq    = (const float*)d_in[3];
    const float* bq    = (const float*)d_in[4];
    const float* wk    = (const float*)d_in[5];
    const float* bk    = (const float*)d_in[6];
    const float* wv    = (const float*)d_in[7];
    const float* bvv   = (const float*)d_in[8];
    const float* wo    = (const float*)d_in[9];
    const float* bo    = (const float*)d_in[10];
    const float* ln2_g = (const float*)d_in[11];
    const float* ln2_b = (const float*)d_in[12];
    const float* w1    = (const float*)d_in[13];
    const float* b1    = (const float*)d_in[14];
    const float* w2    = (const float*)d_in[15];
    const float* b2    = (const float*)d_in[16];

    // ---- workspace layout (~84 MB) ----
    unsigned short* wqkv_b = (unsigned short*)d_ws;                 // 3072*1024
    unsigned short* wo_b   = wqkv_b + 3072 * 1024;                  // 1024*1024
    unsigned short* w1_b   = wo_b + 1024 * 1024;                    // 4096*1024
    unsigned short* w2_b   = w1_b + 4096 * 1024;                    // 1024*4096
    float*          bqkv   = (float*)(w2_b + 1024 * 4096);          // 3072
    unsigned short* region = (unsigned short*)(bqkv + 3072);
    unsigned short* qkvb   = region;                                // 4096*3072
    unsigned short* hb     = region + (size_t)4096 * 3072;          // 4096*1024 (LN1 out)
    unsigned short* vtb    = hb;                                    // 32*64*2048 (hb dead after QKV gemm)
    unsigned short* a1     = region;                                // 4096*4096 (qkv+vt dead after attn)
    unsigned short* attn_o = region + (size_t)4096 * 4096;          // 4096*1024
    unsigned short* h2     = attn_o;                                // alias (attn_o dead when written)
    float*          out1   = (float*)(attn_o + (size_t)4096 * 1024);// 4096*1024 fp32
    float*          outf   = (float*)d_out;

    dim3 blk(256);

    cvt_kernel<<<1024, blk, 0, stream>>>(wq, wqkv_b, 1024 * 1024);
    cvt_kernel<<<1024, blk, 0, stream>>>(wk, wqkv_b + 1024 * 1024, 1024 * 1024);
    cvt_kernel<<<1024, blk, 0, stream>>>(wv, wqkv_b + 2 * 1024 * 1024, 1024 * 1024);
    cvt_kernel<<<1024, blk, 0, stream>>>(wo, wo_b, 1024 * 1024);
    cvt_kernel<<<4096, blk, 0, stream>>>(w1, w1_b, 4096 * 1024);
    cvt_kernel<<<4096, blk, 0, stream>>>(w2, w2_b, 4096 * 1024);
    concat3_kernel<<<12, blk, 0, stream>>>(bq, bk, bvv, bqkv);

    ln_kernel<<<MTOT, blk, 0, stream>>>(x, ln1_g, ln1_b, hb);

    // fused QKV gemm: (4096,1024) @ (3072,1024)^T ; grid 24x32 = 768 blocks
    gemm_kernel<false, false, true><<<768, blk, 0, stream>>>(
        hb, wqkv_b, bqkv, nullptr, qkvb, MTOT, 3072, FEATS, 24);

    vtrans_kernel<<<dim3(BATCH * NH, SEQ / 64), blk, 0, stream>>>(qkvb, vtb);

    attn_kernel<<<dim3(BATCH * NH, SEQ / 128), dim3(512), 0, stream>>>(qkvb, vtb, attn_o);

    // out proj + residual: grid 8x32 = 256 blocks
    gemm_kernel<false, true, false><<<256, blk, 0, stream>>>(
        attn_o, wo_b, bo, x, out1, MTOT, FEATS, FEATS, 8);

    ln_kernel<<<MTOT, blk, 0, stream>>>(out1, ln2_g, ln2_b, h2);

    // MLP1: grid 32x32 = 1024 blocks
    gemm_kernel<true, false, true><<<1024, blk, 0, stream>>>(
        h2, w1_b, b1, nullptr, a1, MTOT, MLPH, FEATS, 32);

    // MLP2: grid 8x32 = 256 blocks
    gemm_kernel<true, true, false><<<256, blk, 0, stream>>>(
        a1, w2_b, b2, out1, outf, MTOT, FEATS, MLPH, 8);
}

// Round 7
// 247.606 us; speedup vs baseline: 1.0755x; 1.0072x over previous
//
#include <hip/hip_runtime.h>
#include <hip/hip_bf16.h>

#define FEATS 1024
#define NH 16
#define HD 64
#define SEQ 2048
#define BATCH 2
#define MTOT (BATCH*SEQ)   // 4096
#define MLPH 4096
// log2(e)/sqrt(FEATS): folded into wq/bq so attn uses exp2f(s) directly
#define QSCALE 0.04508422277369218f

typedef __attribute__((ext_vector_type(8))) short bf16x8;   // 8 bf16 (4 VGPRs)
typedef __attribute__((ext_vector_type(4))) short bf16x4;   // 4 bf16 (2 VGPRs)
typedef __attribute__((ext_vector_type(4))) float f32x4;

static_assert(sizeof(bf16x8) == 16, "bf16x8 must be 16B");

__device__ __forceinline__ unsigned short f2bf(float f) {
    unsigned int u = __float_as_uint(f);
    unsigned int lsb = (u >> 16) & 1u;
    u += 0x7fffu + lsb;              // round-to-nearest-even
    return (unsigned short)(u >> 16);
}

// async global->LDS, 16B per lane. Dest must be wave-uniform base + lane*16.
#define ASYNC16(GP, LP) __builtin_amdgcn_global_load_lds( \
    (const __attribute__((address_space(1))) void*)(GP),  \
    (__attribute__((address_space(3))) void*)(LP), 16, 0, 0)

// ---------------------------------------------------------------- converts
__global__ __launch_bounds__(256) void cvt_kernel(const float* __restrict__ src,
                                                  unsigned short* __restrict__ dst,
                                                  int n, float scale) {
    int i = (blockIdx.x * 256 + threadIdx.x) * 4;
    if (i + 3 < n) {
        float4 v = *(const float4*)(src + i);
        ushort4 o;
        o.x = f2bf(v.x * scale); o.y = f2bf(v.y * scale);
        o.z = f2bf(v.z * scale); o.w = f2bf(v.w * scale);
        *(ushort4*)(dst + i) = o;
    }
}

__global__ __launch_bounds__(256) void concat3_kernel(const float* __restrict__ a,
                                                      const float* __restrict__ b,
                                                      const float* __restrict__ c,
                                                      float* __restrict__ o) {
    int i = blockIdx.x * 256 + threadIdx.x;   // 3072 total
    float v = (i < 1024) ? a[i] * QSCALE : ((i < 2048) ? b[i - 1024] : c[i - 2048]);
    o[i] = v;
}

// ---------------------------------------------------------------- layernorm
__global__ __launch_bounds__(256) void ln_kernel(const float* __restrict__ x,
                                                 const float* __restrict__ g,
                                                 const float* __restrict__ bta,
                                                 unsigned short* __restrict__ h) {
    __shared__ float red[8];
    const int row = blockIdx.x;
    const int t = threadIdx.x;
    const float* xr = x + (size_t)row * FEATS;
    float4 v = ((const float4*)xr)[t];
    float s  = v.x + v.y + v.z + v.w;
    float ss = v.x * v.x + v.y * v.y + v.z * v.z + v.w * v.w;
#pragma unroll
    for (int off = 1; off < 64; off <<= 1) {
        s  += __shfl_xor(s, off);
        ss += __shfl_xor(ss, off);
    }
    const int w = t >> 6;
    if ((t & 63) == 0) { red[w] = s; red[4 + w] = ss; }
    __syncthreads();
    s  = red[0] + red[1] + red[2] + red[3];
    ss = red[4] + red[5] + red[6] + red[7];
    const float mu  = s * (1.f / FEATS);
    const float var = ss * (1.f / FEATS) - mu * mu;
    const float rs  = rsqrtf(var + 1e-5f);
    float4 gv = ((const float4*)g)[t];
    float4 bv = ((const float4*)bta)[t];
    ushort4 ov;
    ov.x = f2bf((v.x - mu) * rs * gv.x + bv.x);
    ov.y = f2bf((v.y - mu) * rs * gv.y + bv.y);
    ov.z = f2bf((v.z - mu) * rs * gv.z + bv.z);
    ov.w = f2bf((v.w - mu) * rs * gv.w + bv.w);
    ((ushort4*)h)[(size_t)row * (FEATS / 4) + t] = ov;
}

// ---------------------------------------------------------------- GEMM
// C[M,N] = epilogue(A[M,K] @ W[N,K]^T + bias); 128x128 tile, BK=32.
// Depth-2 pipeline: 3 LDS buffers, counted vmcnt(4), raw s_barrier.
template <bool RELU, bool ADD, bool OUTBF16>
__global__ __launch_bounds__(256, 3)
void gemm_kernel(const unsigned short* __restrict__ A,
                 const unsigned short* __restrict__ W,
                 const float* __restrict__ bias,
                 const float* __restrict__ addend,
                 void* __restrict__ outp,
                 int M, int N, int K, int gx) {
    __shared__ unsigned short lds[3][2][128 * 32];   // [buf][A=0/B=1][row*32+col]

    const int t = threadIdx.x;
    const int w = t >> 6, lane = t & 63;
    const int wr = w >> 1, wc = w & 1;
    const int li = lane & 15, lj = lane >> 4;

    const int nwg = gridDim.x;
    const int cpx = nwg >> 3;
    const int wg = blockIdx.x;
    const int swz = (wg & 7) * cpx + (wg >> 3);
    const int mb = (swz / gx) * 128, nb = (swz % gx) * 128;

    const int srow = lane >> 2, sc = (lane & 3) * 8;
    const unsigned short* gA = A + (size_t)(mb + w * 16 + srow) * K + sc;
    const unsigned short* gB = W + (size_t)(nb + w * 16 + srow) * K + sc;
    const size_t half = (size_t)64 * K;
    const int lbase = w * 512 + lane * 8;

    const int nt = K >> 5;

#define STAGE(BUF, K0)                                             \
    do {                                                           \
        unsigned short* la_ = &lds[BUF][0][lbase];                 \
        unsigned short* lb_ = &lds[BUF][1][lbase];                 \
        ASYNC16(gA + (K0), la_);                                   \
        ASYNC16(gA + half + (K0), la_ + 2048);                     \
        ASYNC16(gB + (K0), lb_);                                   \
        ASYNC16(gB + half + (K0), lb_ + 2048);                     \
    } while (0)

    STAGE(0, 0);
    STAGE(1, 32);
    asm volatile("s_waitcnt vmcnt(4)" ::: "memory");
    __builtin_amdgcn_s_barrier();

    f32x4 acc[4][4] = {};

    for (int i = 0; i < nt; ++i) {
        const int cur = i % 3;
        const unsigned short* Al = &lds[cur][0][0];
        const unsigned short* Bl = &lds[cur][1][0];

        bf16x8 af[4], bfr[4];
#pragma unroll
        for (int m = 0; m < 4; m++)
            af[m] = *(const bf16x8*)(Al + (wr * 64 + m * 16 + li) * 32 + lj * 8);
#pragma unroll
        for (int n = 0; n < 4; n++)
            bfr[n] = *(const bf16x8*)(Bl + (wc * 64 + n * 16 + li) * 32 + lj * 8);

        const int pf = i + 2 < nt;
        if (pf) STAGE((i + 2) % 3, (i + 2) * 32);

#pragma unroll
        for (int m = 0; m < 4; m++)
#pragma unroll
            for (int n = 0; n < 4; n++)
                acc[m][n] = __builtin_amdgcn_mfma_f32_16x16x32_bf16(af[m], bfr[n], acc[m][n], 0, 0, 0);

        if (i + 1 < nt) {
            if (pf) asm volatile("s_waitcnt vmcnt(4)" ::: "memory");
            else    asm volatile("s_waitcnt vmcnt(0)" ::: "memory");
            __builtin_amdgcn_s_barrier();
        }
    }
#undef STAGE

#pragma unroll
    for (int m = 0; m < 4; m++) {
#pragma unroll
        for (int n = 0; n < 4; n++) {
            const int col = nb + wc * 64 + n * 16 + li;
            const float bv = bias[col];
#pragma unroll
            for (int r = 0; r < 4; r++) {
                const int row = mb + wr * 64 + m * 16 + lj * 4 + r;
                float v = acc[m][n][r] + bv;
                if (RELU) v = fmaxf(v, 0.f);
                if (ADD)  v += addend[(size_t)row * N + col];
                if (OUTBF16)
                    ((unsigned short*)outp)[(size_t)row * N + col] = f2bf(v);
                else
                    ((float*)outp)[(size_t)row * N + col] = v;
            }
        }
    }
}

// ---------------------------------------------------------------- V transpose
__global__ __launch_bounds__(256) void vtrans_kernel(const unsigned short* __restrict__ qkv,
                                                     unsigned short* __restrict__ vt) {
    constexpr int LDV = 68;
    __shared__ unsigned short Vl[64 * LDV];
    const int bh = blockIdx.x, st = blockIdx.y;
    const int b = bh >> 4, h = bh & 15;
    const int t = threadIdx.x;
    const unsigned short* src = qkv + (size_t)(b * SEQ + st * 64) * (3 * FEATS) + 2 * FEATS + h * HD;
#pragma unroll
    for (int i = 0; i < 2; i++) {
        int idx = t + i * 256;
        int r = idx >> 3, c = (idx & 7) * 8;
        *(bf16x8*)(Vl + r * LDV + c) = *(const bf16x8*)(src + (size_t)r * (3 * FEATS) + c);
    }
    __syncthreads();
    unsigned short* dst = vt + (size_t)bh * HD * SEQ + st * 64;
#pragma unroll
    for (int i = 0; i < 2; i++) {
        int idx = t + i * 256;
        int d = idx >> 3, s8 = (idx & 7) * 8;
        bf16x8 v;
#pragma unroll
        for (int j = 0; j < 8; j++) v[j] = Vl[(s8 + j) * LDV + d];
        *(bf16x8*)(dst + (size_t)d * SEQ + s8) = v;
    }
}

// ---------------------------------------------------------------- attention
// 512 thr (8 waves x 16 q-rows), KV tile 128 (16 iters). Swapped QK^T:
// S^T = mfma(K, Q) keeps P lane-local; cvt_pk packs PV A-frags in-register.
// Q pre-scaled by log2e/32 (in wq/bq) -> exp2f(s) directly. Key-slot
// permutation absorbed into V^T staging. T14 issue-early/write-late; T5.
__global__ __launch_bounds__(512, 4)
void attn_kernel(const unsigned short* __restrict__ qkv,
                 const unsigned short* __restrict__ vt,
                 unsigned short* __restrict__ out) {
    constexpr int LK = 72;    // K rows: 64 d + pad (shorts)
    constexpr int LV = 136;   // V^T rows: 128 keys + pad (shorts)
    __shared__ unsigned short Kl[2][128 * LK];
    __shared__ unsigned short Vtl[2][64 * LV];

    const int bh = blockIdx.y;
    const int b = bh >> 4, h = bh & 15;
    const int q0 = blockIdx.x * 128;
    const int t = threadIdx.x, w = t >> 6, lane = t & 63;
    const int li = lane & 15, lj = lane >> 4;

    const size_t rstr = 3 * FEATS;
    const unsigned short* qkvb = qkv + (size_t)(b * SEQ) * rstr;
    const unsigned short* ksrc = qkvb + FEATS + h * HD;
    const unsigned short* vsrc = vt + (size_t)bh * HD * SEQ;

    // Q fragments in registers: B-operand of S^T = K Q^T
    bf16x8 aq[2];
#pragma unroll
    for (int kk = 0; kk < 2; kk++)
        aq[kk] = *(const bf16x8*)(qkvb + (size_t)(q0 + w * 16 + li) * rstr + h * HD + kk * 32 + lj * 8);

    f32x4 o[4] = {};
    float lsum = 0.f;   // denominator for q = li

    // K staging: thread t -> key = t>>2, d-chunk (t&3)*16; two b128
    const int skey = t >> 2, sc = (t & 3) * 16;
    const unsigned short* kg = ksrc + (size_t)skey * rstr + sc;
    const int ldoK = skey * LK + sc;
    // V staging: thread t -> d = t>>3, key-chunk c0 = (t&7)*16; two b128 ->
    // four b64 at permuted slots: pos(k)=(k&96)|(((k>>2)&3)<<3)|(((k>>4)&1)<<2)|(k&3)
    const int sd = t >> 3, c0 = (t & 7) * 16;
    const unsigned short* vg = vsrc + (size_t)sd * SEQ + c0;
    const int posA = (c0 & 96) | (((c0 >> 2) & 3) << 3) | (((c0 >> 4) & 1) << 2);
    const int ldoV = sd * LV + posA;

    const int nt = SEQ / 128;   // 16

#define VSPLIT(VR0, VR1, BUF)                                            \
    do {                                                                 \
        *(bf16x4*)(&Vtl[BUF][ldoV])      = __builtin_shufflevector(VR0, VR0, 0, 1, 2, 3); \
        *(bf16x4*)(&Vtl[BUF][ldoV + 8])  = __builtin_shufflevector(VR0, VR0, 4, 5, 6, 7); \
        *(bf16x4*)(&Vtl[BUF][ldoV + 16]) = __builtin_shufflevector(VR1, VR1, 0, 1, 2, 3); \
        *(bf16x4*)(&Vtl[BUF][ldoV + 24]) = __builtin_shufflevector(VR1, VR1, 4, 5, 6, 7); \
    } while (0)

    // prologue: tile 0 staged
    {
        bf16x8 k0 = *(const bf16x8*)kg;
        bf16x8 k1 = *(const bf16x8*)(kg + 8);
        bf16x8 v0 = *(const bf16x8*)vg;
        bf16x8 v1 = *(const bf16x8*)(vg + 8);
        *(bf16x8*)(&Kl[0][ldoK])     = k0;
        *(bf16x8*)(&Kl[0][ldoK + 8]) = k1;
        VSPLIT(v0, v1, 0);
    }

    int cur = 0;
    for (int i = 0; i < nt; ++i) {
        // issue next tile's global loads early (hidden under this tile's compute)
        bf16x8 kr0, kr1, vr0, vr1;
        if (i + 1 < nt) {
            const unsigned short* kn = kg + (size_t)(i + 1) * 128 * rstr;
            const unsigned short* vn = vg + (i + 1) * 128;
            kr0 = *(const bf16x8*)kn;
            kr1 = *(const bf16x8*)(kn + 8);
            vr0 = *(const bf16x8*)vn;
            vr1 = *(const bf16x8*)(vn + 8);
        }

        // barrier: LDS writes of buf[cur] visible; global loads stay in flight
        asm volatile("s_waitcnt lgkmcnt(0)" ::: "memory");
        __builtin_amdgcn_s_barrier();

        const unsigned short* Kc = Kl[cur];
        const unsigned short* Vc = Vtl[cur];

        // ---- S^T = K Q^T : lane holds S[q=li][key = n*16 + lj*4 + r] ----
        f32x4 s[8];
        __builtin_amdgcn_s_setprio(1);
#pragma unroll
        for (int n = 0; n < 8; n++) {
            bf16x8 k0 = *(const bf16x8*)(Kc + (n * 16 + li) * LK + lj * 8);
            bf16x8 k1 = *(const bf16x8*)(Kc + (n * 16 + li) * LK + 32 + lj * 8);
            f32x4 acc = {};
            acc = __builtin_amdgcn_mfma_f32_16x16x32_bf16(k0, aq[0], acc, 0, 0, 0);
            acc = __builtin_amdgcn_mfma_f32_16x16x32_bf16(k1, aq[1], acc, 0, 0, 0);
            s[n] = acc;
        }
        __builtin_amdgcn_s_setprio(0);

        // ---- p = exp2(s) (pre-scaled); pack PV A-frags in-register ----
        bf16x8 A[4];
#pragma unroll
        for (int kk = 0; kk < 4; kk++) {
            float p[8];
#pragma unroll
            for (int r = 0; r < 4; r++) {
                p[r]     = exp2f(s[2 * kk][r]);
                p[4 + r] = exp2f(s[2 * kk + 1][r]);
                lsum += p[r] + p[4 + r];
            }
            union { unsigned u[4]; bf16x8 v; } Au;
            asm("v_cvt_pk_bf16_f32 %0, %1, %2" : "=v"(Au.u[0]) : "v"(p[0]), "v"(p[1]));
            asm("v_cvt_pk_bf16_f32 %0, %1, %2" : "=v"(Au.u[1]) : "v"(p[2]), "v"(p[3]));
            asm("v_cvt_pk_bf16_f32 %0, %1, %2" : "=v"(Au.u[2]) : "v"(p[4]), "v"(p[5]));
            asm("v_cvt_pk_bf16_f32 %0, %1, %2" : "=v"(Au.u[3]) : "v"(p[6]), "v"(p[7]));
            A[kk] = Au.v;
        }

        // ---- O += P V (V^T rows key-slot-permuted to match A) ----
        __builtin_amdgcn_s_setprio(1);
#pragma unroll
        for (int n = 0; n < 4; n++) {
#pragma unroll
            for (int kk = 0; kk < 4; kk++) {
                bf16x8 bv = *(const bf16x8*)(Vc + (n * 16 + li) * LV + kk * 32 + lj * 8);
                o[n] = __builtin_amdgcn_mfma_f32_16x16x32_bf16(A[kk], bv, o[n], 0, 0, 0);
            }
        }
        __builtin_amdgcn_s_setprio(0);

        // write-late: prefetched tile into the other buffer
        if (i + 1 < nt) {
            *(bf16x8*)(&Kl[cur ^ 1][ldoK])     = kr0;
            *(bf16x8*)(&Kl[cur ^ 1][ldoK + 8]) = kr1;
            VSPLIT(vr0, vr1, cur ^ 1);
        }
        cur ^= 1;
    }
#undef VSPLIT

    // denominator: full sum for q = li lives across lj groups
    lsum += __shfl_xor(lsum, 16);
    lsum += __shfl_xor(lsum, 32);
    const float dinv = 1.f / lsum;
    // epilogue rows are q' = lj*4 + r -> fetch that q's inv via lane shuffle
    float inv[4];
#pragma unroll
    for (int r = 0; r < 4; r++)
        inv[r] = __shfl(dinv, lj * 4 + r);

    unsigned short* ob = out + (size_t)(b * SEQ + q0 + w * 16) * FEATS + h * HD;
#pragma unroll
    for (int n = 0; n < 4; n++)
#pragma unroll
        for (int r = 0; r < 4; r++)
            ob[(size_t)(lj * 4 + r) * FEATS + n * 16 + li] = f2bf(o[n][r] * inv[r]);
}

// ---------------------------------------------------------------- launch
extern "C" void kernel_launch(void* const* d_in, const int* in_sizes, int n_in,
                              void* d_out, int out_size, void* d_ws, size_t ws_size,
                              hipStream_t stream) {
    const float* x     = (const float*)d_in[0];
    const float* ln1_g = (const float*)d_in[1];
    const float* ln1_b = (const float*)d_in[2];
    const float* wq    = (const float*)d_in[3];
    const float* bq    = (const float*)d_in[4];
    const float* wk    = (const float*)d_in[5];
    const float* bk    = (const float*)d_in[6];
    const float* wv    = (const float*)d_in[7];
    const float* bvv   = (const float*)d_in[8];
    const float* wo    = (const float*)d_in[9];
    const float* bo    = (const float*)d_in[10];
    const float* ln2_g = (const float*)d_in[11];
    const float* ln2_b = (const float*)d_in[12];
    const float* w1    = (const float*)d_in[13];
    const float* b1    = (const float*)d_in[14];
    const float* w2    = (const float*)d_in[15];
    const float* b2    = (const float*)d_in[16];

    // ---- workspace layout (~84 MB) ----
    unsigned short* wqkv_b = (unsigned short*)d_ws;                 // 3072*1024
    unsigned short* wo_b   = wqkv_b + 3072 * 1024;                  // 1024*1024
    unsigned short* w1_b   = wo_b + 1024 * 1024;                    // 4096*1024
    unsigned short* w2_b   = w1_b + 4096 * 1024;                    // 1024*4096
    float*          bqkv   = (float*)(w2_b + 1024 * 4096);          // 3072
    unsigned short* region = (unsigned short*)(bqkv + 3072);
    unsigned short* qkvb   = region;                                // 4096*3072
    unsigned short* hb     = region + (size_t)4096 * 3072;          // 4096*1024 (LN1 out)
    unsigned short* vtb    = hb;                                    // 32*64*2048 (hb dead after QKV gemm)
    unsigned short* a1     = region;                                // 4096*4096 (qkv+vt dead after attn)
    unsigned short* attn_o = region + (size_t)4096 * 4096;          // 4096*1024
    unsigned short* h2     = attn_o;                                // alias (attn_o dead when written)
    float*          out1   = (float*)(attn_o + (size_t)4096 * 1024);// 4096*1024 fp32
    float*          outf   = (float*)d_out;

    dim3 blk(256);

    cvt_kernel<<<1024, blk, 0, stream>>>(wq, wqkv_b, 1024 * 1024, QSCALE);
    cvt_kernel<<<1024, blk, 0, stream>>>(wk, wqkv_b + 1024 * 1024, 1024 * 1024, 1.0f);
    cvt_kernel<<<1024, blk, 0, stream>>>(wv, wqkv_b + 2 * 1024 * 1024, 1024 * 1024, 1.0f);
    cvt_kernel<<<1024, blk, 0, stream>>>(wo, wo_b, 1024 * 1024, 1.0f);
    cvt_kernel<<<4096, blk, 0, stream>>>(w1, w1_b, 4096 * 1024, 1.0f);
    cvt_kernel<<<4096, blk, 0, stream>>>(w2, w2_b, 4096 * 1024, 1.0f);
    concat3_kernel<<<12, blk, 0, stream>>>(bq, bk, bvv, bqkv);

    ln_kernel<<<MTOT, blk, 0, stream>>>(x, ln1_g, ln1_b, hb);

    // fused QKV gemm: (4096,1024) @ (3072,1024)^T ; grid 24x32 = 768 blocks
    gemm_kernel<false, false, true><<<768, blk, 0, stream>>>(
        hb, wqkv_b, bqkv, nullptr, qkvb, MTOT, 3072, FEATS, 24);

    vtrans_kernel<<<dim3(BATCH * NH, SEQ / 64), blk, 0, stream>>>(qkvb, vtb);

    attn_kernel<<<dim3(SEQ / 128, BATCH * NH), dim3(512), 0, stream>>>(qkvb, vtb, attn_o);

    // out proj + residual: grid 8x32 = 256 blocks
    gemm_kernel<false, true, false><<<256, blk, 0, stream>>>(
        attn_o, wo_b, bo, x, out1, MTOT, FEATS, FEATS, 8);

    ln_kernel<<<MTOT, blk, 0, stream>>>(out1, ln2_g, ln2_b, h2);

    // MLP1: grid 32x32 = 1024 blocks
    gemm_kernel<true, false, true><<<1024, blk, 0, stream>>>(
        h2, w1_b, b1, nullptr, a1, MTOT, MLPH, FEATS, 32);

    // MLP2: grid 8x32 = 256 blocks
    gemm_kernel<true, true, false><<<256, blk, 0, stream>>>(
        a1, w2_b, b2, out1, outf, MTOT, FEATS, MLPH, 8);
}